// Round 10
// baseline (401.210 us; speedup 1.0000x reference)
//
#include <hip/hip_runtime.h>
#include <string.h>

typedef _Float16 f16x8 __attribute__((ext_vector_type(8)));
typedef float f32x4 __attribute__((ext_vector_type(4)));

#define EXP_CLIP 10.0f
#define FEPS 1e-6f
#define WSCALE 16384.0f      // 2^14 weight prescale (kills fp16-denorm weights)
#define WDESCALE (1.0f/16384.0f)
#define PSCALE 1024.0f       // proj weight prescale
#define PDESCALE (1.0f/1024.0f)

__device__ __forceinline__ _Float16 cvh(float v) {
  v = fminf(fmaxf(v, -60000.f), 60000.f);
  return (_Float16)v;
}

__device__ __forceinline__ void gload_lds16(const void* g, void* l) {
  __builtin_amdgcn_global_load_lds(
      (const __attribute__((address_space(1))) void*)g,
      (__attribute__((address_space(3))) void*)l, 16, 0, 0);
}

// XOR-swizzled LDS offset (half units) for a [*][64]-half tile.
__device__ __forceinline__ int swz(int row, int colh) {
  return row * 64 + (colh ^ ((row & 7) << 3));
}

__device__ __forceinline__ float prim_eval(int kp, float x) {
  switch (kp) {
    case 0: return x;
    case 1: return x * x;
    case 2: return x * x * x;
    case 3: return __expf(fminf(fmaxf(x, -EXP_CLIP), EXP_CLIP));
    case 4: return __logf(fabsf(x) + FEPS);
    case 5: return x / (x * x + FEPS);
    default: return __sinf(x);
  }
}

// e5m2 encode (RNE) of a small residual: fp16 bits -> top byte with rounding.
__device__ __forceinline__ unsigned char enc_e5m2(float lo) {
  _Float16 lh = (_Float16)lo;
  unsigned short u;
  memcpy(&u, &lh, 2);
  unsigned t = (unsigned)u + 0x7Fu + ((u >> 8) & 1u);
  return (unsigned char)(t >> 8);
}

// ---------------------------------------------------------------------------
// Fused prep: blocks 0..511 = layer-0 softmax/scale (emit lo), 512..1023 =
// layer-1 (no lo), 1024..1055 = proj-weight fp16 convert (x8 vectorized).
// ---------------------------------------------------------------------------
__global__ __launch_bounds__(512)
void prep_all(const float* __restrict__ a0, const float* __restrict__ s0,
              const float* __restrict__ b0, _Float16* __restrict__ Wh0,
              _Float16* __restrict__ Wl0,
              const float* __restrict__ a1, const float* __restrict__ s1,
              const float* __restrict__ b1, _Float16* __restrict__ Wh1,
              const float* __restrict__ W, _Float16* __restrict__ WpT,
              float* __restrict__ biasvec) {
  int blk = blockIdx.x;
  int i = threadIdx.x;
  if (blk >= 1024) {
    // proj convert: 32 blocks x 512 thr x 8 elems = 131072
    int idx = ((blk - 1024) * 512 + i) * 8;
    float4 v0 = *(const float4*)(W + idx);
    float4 v1 = *(const float4*)(W + idx + 4);
    f16x8 o;
    o[0] = (_Float16)(v0.x * PSCALE); o[1] = (_Float16)(v0.y * PSCALE);
    o[2] = (_Float16)(v0.z * PSCALE); o[3] = (_Float16)(v0.w * PSCALE);
    o[4] = (_Float16)(v1.x * PSCALE); o[5] = (_Float16)(v1.y * PSCALE);
    o[6] = (_Float16)(v1.z * PSCALE); o[7] = (_Float16)(v1.w * PSCALE);
    *(f16x8*)&WpT[idx] = o;
    return;
  }
  bool l0 = blk < 512;
  int j = l0 ? blk : blk - 512;
  const float* alphas = l0 ? a0 : a1;
  const float* scale  = l0 ? s0 : s1;
  const float* bias   = l0 ? b0 : b1;
  _Float16* Wh = l0 ? Wh0 : Wh1;
  float* bvec = biasvec + (l0 ? 0 : 512);

  size_t base = ((size_t)i * 512 + j) * 8;
  float a[8];
#pragma unroll
  for (int k = 0; k < 8; ++k) a[k] = alphas[base + k];
  float m = a[0];
#pragma unroll
  for (int k = 1; k < 8; ++k) m = fmaxf(m, a[k]);
  float e[8], sum = 0.f;
#pragma unroll
  for (int k = 0; k < 8; ++k) { e[k] = __expf(a[k] - m); sum += e[k]; }
  float inv = 1.f / sum;
  float bp = 0.f;
#pragma unroll
  for (int k = 1; k < 8; ++k) {
    float w = e[k] * inv;
    float ws = fminf(fmaxf(w * scale[base + k] * WSCALE, -60000.f), 60000.f);
    _Float16 wh = (_Float16)ws;
    size_t o = (size_t)j * 3584 + (size_t)(k - 1) * 512 + i;
    Wh[o] = wh;
    if (l0) Wl0[o] = (_Float16)(ws - (float)wh);
    bp += w * bias[base + k];
  }
  __shared__ float red[512];
  red[i] = bp;
  __syncthreads();
  for (int off = 256; off > 0; off >>= 1) {
    if (i < off) red[i] += red[i + off];
    __syncthreads();
  }
  if (i == 0) bvec[j] = red[0];
}

// ---------------------------------------------------------------------------
// Pre-featurize x -> Fhi fp16 + FloB e5m2-byte, both [16384][3584].
// ---------------------------------------------------------------------------
__global__ __launch_bounds__(256)
void featurize_hilo(const float* __restrict__ in, _Float16* __restrict__ hi,
                    unsigned char* __restrict__ loB) {
  int t = blockIdx.x * 256 + threadIdx.x;    // 16384*64 threads
  int b = t >> 6, g = (t & 63) * 8;
  const float* xp = in + (size_t)b * 512 + g;
  float4 a = *(const float4*)xp;
  float4 c = *(const float4*)(xp + 4);
  float xv[8] = {a.x, a.y, a.z, a.w, c.x, c.y, c.z, c.w};
  _Float16* oh = hi + (size_t)b * 3584 + g;
  unsigned char* ol = loB + (size_t)b * 3584 + g;
#pragma unroll
  for (int kp = 0; kp < 7; ++kp) {
    f16x8 hv;
    unsigned long long lb = 0;
#pragma unroll
    for (int e = 0; e < 8; ++e) {
      float f = prim_eval(kp, xv[e]);
      _Float16 fh = (_Float16)f;
      hv[e] = fh;
      lb |= (unsigned long long)enc_e5m2(f - (float)fh) << (8 * e);
    }
    *(f16x8*)&oh[kp * 512] = hv;
    *(unsigned long long*)&ol[kp * 512] = lb;
  }
}

// ---------------------------------------------------------------------------
// Featurize (layer-2 input): h [rows][512] fp32 -> out [rows][3584] fp16.
// ---------------------------------------------------------------------------
__global__ __launch_bounds__(256)
void featurize8(const float* __restrict__ in, _Float16* __restrict__ out) {
  int t = blockIdx.x * 256 + threadIdx.x;
  int b = t >> 6, g = (t & 63) * 8;
  const float* xp = in + (size_t)b * 512 + g;
  float4 a = *(const float4*)xp;
  float4 c = *(const float4*)(xp + 4);
  float xv[8] = {a.x, a.y, a.z, a.w, c.x, c.y, c.z, c.w};
  _Float16* o = out + (size_t)b * 3584 + g;
#pragma unroll
  for (int kp = 0; kp < 7; ++kp) {
    f16x8 v;
#pragma unroll
    for (int e = 0; e < 8; ++e) v[e] = cvh(prim_eval(kp, xv[e]));
    *(f16x8*)&o[kp * 512] = v;
  }
}

// ---------------------------------------------------------------------------
// Layer-1 GEMM (round-7 proven): 3-term split GEMM on pre-featurized A.
// A-hi fp16 (swizzled), A-lo e5m2 bytes (16B-pair XOR-swizzled), B-hi/lo
// fp16 (swizzled). 128x128, BK=64, 4 waves, 56 KB LDS (2 blk/CU), 2-phase.
// ---------------------------------------------------------------------------
__global__ __launch_bounds__(256)
void gemm_l1_pre(const _Float16* __restrict__ Fhi, const unsigned char* __restrict__ FloB,
                 const _Float16* __restrict__ Wh, const _Float16* __restrict__ Wl,
                 const float* __restrict__ bias, float* __restrict__ H) {
  __shared__ __align__(16) _Float16 AhS[128 * 64];       // 16 KB
  __shared__ __align__(16) unsigned char AlB[128 * 64];  //  8 KB
  __shared__ __align__(16) _Float16 BhS[128 * 64];       // 16 KB
  __shared__ __align__(16) _Float16 BlS[128 * 64];       // 16 KB
  const int K = 3584;
  int lin = blockIdx.x;                 // 512 blocks
  int wg = (lin & 7) * 64 + (lin >> 3); // XCD-contiguous remap
  int bn = wg & 3, bm = wg >> 2;        // bn fast: col-blocks share A panel in XCD-L2
  int row0 = bm * 128, col0 = bn * 128;
  int tid = threadIdx.x, lane = tid & 63, wave = tid >> 6;
  int wm = wave >> 1, wn = wave & 1;
  int l16 = lane & 15, lh = lane >> 4;
  int sr = lane >> 3, sc = ((lane & 7) * 8) ^ (sr << 3);  // pre-swz src col (halves)
  int br = lane >> 2, bp_ = lane & 3;
  int bcs = (bp_ ^ ((br >> 1) & 3)) * 16;                 // pre-swz src col (bytes)

  f32x4 acc[4][4];
#pragma unroll
  for (int m = 0; m < 4; ++m)
#pragma unroll
    for (int n = 0; n < 4; ++n) acc[m][n] = (f32x4){0.f, 0.f, 0.f, 0.f};

  for (int kk0 = 0; kk0 < K; kk0 += 64) {
    const _Float16* Agh = Fhi + (size_t)row0 * K + kk0;
    const unsigned char* Agl = FloB + (size_t)row0 * K + kk0;
    const _Float16* Bgh = Wh + (size_t)col0 * K + kk0;
    const _Float16* Bgl = Wl + (size_t)col0 * K + kk0;
#pragma unroll
    for (int it = 0; it < 4; ++it) {
      int chunk = it * 4 + wave;          // 0..15
      int r = chunk * 8 + sr;
      size_t go = (size_t)r * K + sc;
      gload_lds16(Agh + go, AhS + chunk * 512);
      gload_lds16(Bgh + go, BhS + chunk * 512);
      gload_lds16(Bgl + go, BlS + chunk * 512);
    }
#pragma unroll
    for (int it = 0; it < 2; ++it) {
      int chunk = it * 4 + wave;          // 0..7, 16 rows each
      int r = chunk * 16 + br;
      gload_lds16(Agl + (size_t)r * K + bcs, AlB + chunk * 1024);
    }
    __syncthreads();
#pragma unroll
    for (int kc = 0; kc < 2; ++kc) {
      f16x8 ah[4], al[4];
#pragma unroll
      for (int m = 0; m < 4; ++m) {
        int row = wm * 64 + m * 16 + l16;
        ah[m] = *(const f16x8*)&AhS[swz(row, kc * 32 + lh * 8)];
        // A-lo: 8 e5m2 bytes (pair-swizzled) -> 8 fp16 (byte<<8)
        int cbyte = (kc * 32 + lh * 8) ^ (((row >> 1) & 3) << 4);
        uint2 d = *(const uint2*)&AlB[row * 64 + cbyte];
        union { unsigned u[4]; f16x8 v; } ex;
        ex.u[0] = ((d.x << 8) & 0xFF00u) | ((d.x << 16) & 0xFF000000u);
        ex.u[1] = ((d.x >> 8) & 0xFF00u) | (d.x & 0xFF000000u);
        ex.u[2] = ((d.y << 8) & 0xFF00u) | ((d.y << 16) & 0xFF000000u);
        ex.u[3] = ((d.y >> 8) & 0xFF00u) | (d.y & 0xFF000000u);
        al[m] = ex.v;
      }
#pragma unroll
      for (int n = 0; n < 4; ++n) {
        int ob = swz(wn * 64 + n * 16 + l16, kc * 32 + lh * 8);
        f16x8 bh = *(const f16x8*)&BhS[ob];
        f16x8 bl = *(const f16x8*)&BlS[ob];
#pragma unroll
        for (int m = 0; m < 4; ++m) {
          acc[m][n] = __builtin_amdgcn_mfma_f32_16x16x32_f16(ah[m], bh, acc[m][n], 0, 0, 0);
          acc[m][n] = __builtin_amdgcn_mfma_f32_16x16x32_f16(al[m], bh, acc[m][n], 0, 0, 0);
          acc[m][n] = __builtin_amdgcn_mfma_f32_16x16x32_f16(ah[m], bl, acc[m][n], 0, 0, 0);
        }
      }
    }
    __syncthreads();
  }

#pragma unroll
  for (int m = 0; m < 4; ++m) {
    int row = row0 + wm * 64 + m * 16 + lh * 4;
#pragma unroll
    for (int n = 0; n < 4; ++n) {
      int col = col0 + wn * 64 + n * 16 + l16;
      float bv = bias[col];
#pragma unroll
      for (int r = 0; r < 4; ++r)
        H[(size_t)(row + r) * 512 + col] = acc[m][n][r] * WDESCALE + bv;
    }
  }
}

// ---------------------------------------------------------------------------
// Layer-1 fused GEMM (pipeline B fallback, proven): featurize in-loop.
// ---------------------------------------------------------------------------
__global__ __launch_bounds__(256, 2)
void gemm_l1_fused(const float* __restrict__ X, const _Float16* __restrict__ Wh,
                   const _Float16* __restrict__ Wl, const float* __restrict__ bias,
                   float* __restrict__ H) {
  __shared__ __align__(16) _Float16 AhS[128 * 64];
  __shared__ __align__(16) _Float16 AlS[128 * 64];
  __shared__ __align__(16) _Float16 BhS[128 * 64];
  __shared__ __align__(16) _Float16 BlS[128 * 64];
  const int K = 3584;
  int lin = blockIdx.x;
  int wg = (lin & 7) * 64 + (lin >> 3);
  int bn = wg & 3, bm = wg >> 2;
  int row0 = bm * 128, col0 = bn * 128;
  int tid = threadIdx.x, lane = tid & 63, wave = tid >> 6;
  int wm = wave >> 1, wn = wave & 1;
  int l16 = lane & 15, lh = lane >> 4;
  int sr = lane >> 3, sc = ((lane & 7) * 8) ^ (sr << 3);
  int ar = tid >> 3, ac = (tid & 7) * 8;

  f32x4 acc[4][4];
#pragma unroll
  for (int m = 0; m < 4; ++m)
#pragma unroll
    for (int n = 0; n < 4; ++n) acc[m][n] = (f32x4){0.f, 0.f, 0.f, 0.f};

#pragma unroll 1
  for (int kk0 = 0; kk0 < K; kk0 += 64) {
    int kp = kk0 >> 9, i0 = kk0 & 511;
    const _Float16* Bgh = Wh + (size_t)col0 * K + kk0;
    const _Float16* Bgl = Wl + (size_t)col0 * K + kk0;
#pragma unroll
    for (int it = 0; it < 4; ++it) {
      int chunk = it * 4 + wave;
      int r = chunk * 8 + sr;
      gload_lds16(Bgh + (size_t)r * K + sc, BhS + chunk * 512);
      gload_lds16(Bgl + (size_t)r * K + sc, BlS + chunk * 512);
    }
#pragma unroll
    for (int it = 0; it < 4; ++it) {
      int r = it * 32 + ar;
      const float* xp = X + (size_t)(row0 + r) * 512 + i0 + ac;
      float4 x01 = *(const float4*)xp;
      float4 x23 = *(const float4*)(xp + 4);
      float xv[8] = {x01.x, x01.y, x01.z, x01.w, x23.x, x23.y, x23.z, x23.w};
      f16x8 hv, lv;
#pragma unroll
      for (int e = 0; e < 8; ++e) {
        float f = prim_eval(kp, xv[e]);
        _Float16 fh = (_Float16)f;
        hv[e] = fh;
        lv[e] = (_Float16)(f - (float)fh);
      }
      int wo = swz(r, ac);
      *(f16x8*)&AhS[wo] = hv;
      *(f16x8*)&AlS[wo] = lv;
    }
    __syncthreads();
#pragma unroll
    for (int kc = 0; kc < 2; ++kc) {
      f16x8 ah[4], al[4];
#pragma unroll
      for (int m = 0; m < 4; ++m) {
        int off = swz(wm * 64 + m * 16 + l16, kc * 32 + lh * 8);
        ah[m] = *(const f16x8*)&AhS[off];
        al[m] = *(const f16x8*)&AlS[off];
      }
#pragma unroll
      for (int n = 0; n < 4; ++n) {
        int ob = swz(wn * 64 + n * 16 + l16, kc * 32 + lh * 8);
        f16x8 bh = *(const f16x8*)&BhS[ob];
        f16x8 bl = *(const f16x8*)&BlS[ob];
#pragma unroll
        for (int m = 0; m < 4; ++m) {
          acc[m][n] = __builtin_amdgcn_mfma_f32_16x16x32_f16(ah[m], bh, acc[m][n], 0, 0, 0);
          acc[m][n] = __builtin_amdgcn_mfma_f32_16x16x32_f16(al[m], bh, acc[m][n], 0, 0, 0);
          acc[m][n] = __builtin_amdgcn_mfma_f32_16x16x32_f16(ah[m], bl, acc[m][n], 0, 0, 0);
        }
      }
    }
    __syncthreads();
  }

#pragma unroll
  for (int m = 0; m < 4; ++m) {
    int row = row0 + wm * 64 + m * 16 + lh * 4;
#pragma unroll
    for (int n = 0; n < 4; ++n) {
      int col = col0 + wn * 64 + n * 16 + l16;
      float bv = bias[col];
#pragma unroll
      for (int r = 0; r < 4; ++r)
        H[(size_t)(row + r) * 512 + col] = acc[m][n][r] * WDESCALE + bv;
    }
  }
}

// ---------------------------------------------------------------------------
// Plain fp16 GEMM (16x16, proven): C = A * BT^T * outscale + bias[N].
// ---------------------------------------------------------------------------
template <bool OUT_HALF>
__global__ __launch_bounds__(256)
void gemm_tn(const _Float16* __restrict__ A, const _Float16* __restrict__ BT,
             const float* __restrict__ bias, void* __restrict__ C,
             int M, int N, int K, int nbn_log2, int nwg, float outscale) {
  __shared__ __align__(16) _Float16 Ash[128 * 64];
  __shared__ __align__(16) _Float16 Bsh[128 * 64];
  int lin = blockIdx.x;
  int q = nwg >> 3;
  int wg = (lin & 7) * q + (lin >> 3);
  int bn = wg & ((1 << nbn_log2) - 1);
  int bm = wg >> nbn_log2;
  int row0 = bm * 128, col0 = bn * 128;
  int tid = threadIdx.x, lane = tid & 63, wave = tid >> 6;
  int wm = wave >> 1, wn = wave & 1;
  int l16 = lane & 15, lh = lane >> 4;
  int sr = lane >> 3;
  int sc = ((lane & 7) * 8) ^ (sr << 3);

  f32x4 acc[4][4];
#pragma unroll
  for (int m = 0; m < 4; ++m)
#pragma unroll
    for (int n = 0; n < 4; ++n) acc[m][n] = (f32x4){0.f, 0.f, 0.f, 0.f};

  for (int kk0 = 0; kk0 < K; kk0 += 64) {
    const _Float16* Ag = A + (size_t)row0 * K + kk0;
    const _Float16* Bg = BT + (size_t)col0 * K + kk0;
#pragma unroll
    for (int it = 0; it < 4; ++it) {
      int chunk = it * 4 + wave;
      int r = chunk * 8 + sr;
      gload_lds16(Ag + (size_t)r * K + sc, Ash + chunk * 512);
      gload_lds16(Bg + (size_t)r * K + sc, Bsh + chunk * 512);
    }
    __syncthreads();
#pragma unroll
    for (int kc = 0; kc < 2; ++kc) {
      f16x8 af[4], bf[4];
#pragma unroll
      for (int m = 0; m < 4; ++m)
        af[m] = *(const f16x8*)&Ash[swz(wm * 64 + m * 16 + l16, kc * 32 + lh * 8)];
#pragma unroll
      for (int n = 0; n < 4; ++n)
        bf[n] = *(const f16x8*)&Bsh[swz(wn * 64 + n * 16 + l16, kc * 32 + lh * 8)];
#pragma unroll
      for (int m = 0; m < 4; ++m)
#pragma unroll
        for (int n = 0; n < 4; ++n)
          acc[m][n] = __builtin_amdgcn_mfma_f32_16x16x32_f16(af[m], bf[n], acc[m][n], 0, 0, 0);
    }
    __syncthreads();
  }

#pragma unroll
  for (int m = 0; m < 4; ++m) {
    int row = row0 + wm * 64 + m * 16 + lh * 4;
#pragma unroll
    for (int n = 0; n < 4; ++n) {
      int col = col0 + wn * 64 + n * 16 + l16;
      float bv = bias[col];
#pragma unroll
      for (int r = 0; r < 4; ++r) {
        float v = acc[m][n][r] * outscale + bv;
        if (OUT_HALF)
          ((_Float16*)C)[(size_t)(row + r) * N + col] = cvh(v);
        else
          ((float*)C)[(size_t)(row + r) * N + col] = v;
      }
    }
  }
}

// ---------------------------------------------------------------------------
extern "C" void kernel_launch(void* const* d_in, const int* in_sizes, int n_in,
                              void* d_out, int out_size, void* d_ws, size_t ws_size,
                              hipStream_t stream) {
  const float* x  = (const float*)d_in[0];
  const float* a0 = (const float*)d_in[1];
  const float* s0 = (const float*)d_in[2];
  const float* b0 = (const float*)d_in[3];
  const float* a1 = (const float*)d_in[4];
  const float* s1 = (const float*)d_in[5];
  const float* b1 = (const float*)d_in[6];
  const float* W  = (const float*)d_in[7];
  const float* bb = (const float*)d_in[8];

  const int Bn = 16384, D = 512, KK = 3584, DOUT = 256;
  const size_t szF  = (size_t)Bn * KK * 2;  // 117,440,512
  const size_t szFb = (size_t)Bn * KK;      //  58,720,256 (byte lo)
  const size_t szH  = (size_t)Bn * D * 4;   //  33,554,432
  const size_t szW  = (size_t)D * KK * 2;   //   3,670,016
  const size_t szP  = (size_t)DOUT * D * 2; //     262,144
  const size_t needA = szF + szFb + szH + 3 * szW + szP + 4096;  // ~221.0 MB

  if (ws_size >= needA) {
    // ---- pipeline A: pre-featurized hi/byte-lo (round-7 proven) ----
    char* p = (char*)d_ws;
    _Float16*      Fhi  = (_Float16*)p; p += szF;       // reused as layer-2 Afeat
    unsigned char* FloB = (unsigned char*)p; p += szFb;
    float*    h     = (float*)p;
    _Float16* ghalf = (_Float16*)p; p += szH;
    _Float16* Wh0   = (_Float16*)p; p += szW;
    _Float16* Wl0   = (_Float16*)p; p += szW;
    _Float16* Wh1   = (_Float16*)p; p += szW;
    _Float16* WpT   = (_Float16*)p; p += szP;
    float*    biasv = (float*)p;

    prep_all<<<dim3(1056), dim3(512), 0, stream>>>(a0, s0, b0, Wh0, Wl0,
                                                   a1, s1, b1, Wh1, W, WpT, biasv);

    featurize_hilo<<<dim3(Bn * 64 / 256), dim3(256), 0, stream>>>(x, Fhi, FloB);
    gemm_l1_pre<<<dim3(512), dim3(256), 0, stream>>>(Fhi, FloB, Wh0, Wl0, biasv, h);

    featurize8<<<dim3(Bn * 64 / 256), dim3(256), 0, stream>>>(h, Fhi);
    gemm_tn<true><<<dim3(512), dim3(256), 0, stream>>>(Fhi, Wh1, biasv + 512, ghalf,
                                                       Bn, D, KK, 2, 512, WDESCALE);

    gemm_tn<false><<<dim3(256), dim3(256), 0, stream>>>(ghalf, WpT, bb, (float*)d_out,
                                                        Bn, DOUT, D, 1, 256, PDESCALE);
  } else {
    // ---- pipeline B (proven fallback): fused featurize layer-1 ----
    char* p = (char*)d_ws;
    _Float16* Afeat = (_Float16*)p;
    _Float16* Wh0   = (_Float16*)p;
    _Float16* Wl0   = (_Float16*)(p + szW);
    p += szF;
    float*    h     = (float*)p;
    _Float16* ghalf = (_Float16*)p;
    p += szH;
    _Float16* Wh1   = (_Float16*)p; p += szW;
    _Float16* WpT   = (_Float16*)p; p += szP;
    float*    biasv = (float*)p;

    prep_all<<<dim3(1056), dim3(512), 0, stream>>>(a0, s0, b0, Wh0, Wl0,
                                                   a1, s1, b1, Wh1, W, WpT, biasv);

    gemm_l1_fused<<<dim3(512), dim3(256), 0, stream>>>(x, Wh0, Wl0, biasv, h);

    featurize8<<<dim3(Bn * 64 / 256), dim3(256), 0, stream>>>(h, Afeat);
    gemm_tn<true><<<dim3(512), dim3(256), 0, stream>>>(Afeat, Wh1, biasv + 512, ghalf,
                                                       Bn, D, KK, 2, 512, WDESCALE);

    gemm_tn<false><<<dim3(256), dim3(256), 0, stream>>>(ghalf, WpT, bb, (float*)d_out,
                                                        Bn, DOUT, D, 1, 256, PDESCALE);
  }
}

// Round 11
// 330.638 us; speedup vs baseline: 1.2134x; 1.2134x over previous
//
#include <hip/hip_runtime.h>
#include <string.h>

typedef _Float16 f16x8 __attribute__((ext_vector_type(8)));
typedef float f32x4 __attribute__((ext_vector_type(4)));

#define EXP_CLIP 10.0f
#define FEPS 1e-6f
#define WSCALE 16384.0f      // 2^14 weight prescale (kills fp16-denorm weights)
#define WDESCALE (1.0f/16384.0f)
#define PSCALE 1024.0f       // proj weight prescale
#define PDESCALE (1.0f/1024.0f)

__device__ __forceinline__ _Float16 cvh(float v) {
  v = fminf(fmaxf(v, -60000.f), 60000.f);
  return (_Float16)v;
}

__device__ __forceinline__ void gload_lds16(const void* g, void* l) {
  __builtin_amdgcn_global_load_lds(
      (const __attribute__((address_space(1))) void*)g,
      (__attribute__((address_space(3))) void*)l, 16, 0, 0);
}

// XOR-swizzled LDS offset (half units) for a [*][64]-half tile.
__device__ __forceinline__ int swz(int row, int colh) {
  return row * 64 + (colh ^ ((row & 7) << 3));
}

__device__ __forceinline__ float prim_eval(int kp, float x) {
  switch (kp) {
    case 0: return x;
    case 1: return x * x;
    case 2: return x * x * x;
    case 3: return __expf(fminf(fmaxf(x, -EXP_CLIP), EXP_CLIP));
    case 4: return __logf(fabsf(x) + FEPS);
    case 5: return x / (x * x + FEPS);
    default: return __sinf(x);
  }
}

// e5m2 encode (RNE) of a small residual: fp16 bits -> top byte with rounding.
__device__ __forceinline__ unsigned char enc_e5m2(float lo) {
  _Float16 lh = (_Float16)lo;
  unsigned short u;
  memcpy(&u, &lh, 2);
  unsigned t = (unsigned)u + 0x7Fu + ((u >> 8) & 1u);
  return (unsigned char)(t >> 8);
}

// pipeline tail sync for gemm_tn_pipe (r8-proven): drain, raw barrier, pin.
#define PIPE_TAIL() do { \
  __builtin_amdgcn_sched_barrier(0); \
  asm volatile("s_waitcnt vmcnt(0)" ::: "memory"); \
  __builtin_amdgcn_s_barrier(); \
  __builtin_amdgcn_sched_barrier(0); \
} while (0)

// ---------------------------------------------------------------------------
// Prep: per (layer, j) block, 512 threads over i.  (r7-proven)
// ---------------------------------------------------------------------------
template <bool EMIT_LO>
__global__ __launch_bounds__(512)
void prep_weights(const float* __restrict__ alphas, const float* __restrict__ scale,
                  const float* __restrict__ bias, _Float16* __restrict__ Wh,
                  _Float16* __restrict__ Wl, float* __restrict__ biasvec) {
  int j = blockIdx.x;
  int i = threadIdx.x;
  size_t base = ((size_t)i * 512 + j) * 8;
  float a[8];
#pragma unroll
  for (int k = 0; k < 8; ++k) a[k] = alphas[base + k];
  float m = a[0];
#pragma unroll
  for (int k = 1; k < 8; ++k) m = fmaxf(m, a[k]);
  float e[8], sum = 0.f;
#pragma unroll
  for (int k = 0; k < 8; ++k) { e[k] = __expf(a[k] - m); sum += e[k]; }
  float inv = 1.f / sum;
  float bp = 0.f;
#pragma unroll
  for (int k = 1; k < 8; ++k) {
    float w = e[k] * inv;
    float ws = fminf(fmaxf(w * scale[base + k] * WSCALE, -60000.f), 60000.f);
    _Float16 wh = (_Float16)ws;
    size_t o = (size_t)j * 3584 + (size_t)(k - 1) * 512 + i;
    Wh[o] = wh;
    if (EMIT_LO) Wl[o] = (_Float16)(ws - (float)wh);
    bp += w * bias[base + k];
  }
  __shared__ float red[512];
  red[i] = bp;
  __syncthreads();
  for (int off = 256; off > 0; off >>= 1) {
    if (i < off) red[i] += red[i + off];
    __syncthreads();
  }
  if (i == 0) biasvec[j] = red[0];
}

// ---------------------------------------------------------------------------
// Pre-featurize x -> Fhi fp16 + FloB e5m2-byte, both [16384][3584].
// ---------------------------------------------------------------------------
__global__ __launch_bounds__(256)
void featurize_hilo(const float* __restrict__ in, _Float16* __restrict__ hi,
                    unsigned char* __restrict__ loB) {
  int t = blockIdx.x * 256 + threadIdx.x;    // 16384*64 threads
  int b = t >> 6, g = (t & 63) * 8;
  const float* xp = in + (size_t)b * 512 + g;
  float4 a = *(const float4*)xp;
  float4 c = *(const float4*)(xp + 4);
  float xv[8] = {a.x, a.y, a.z, a.w, c.x, c.y, c.z, c.w};
  _Float16* oh = hi + (size_t)b * 3584 + g;
  unsigned char* ol = loB + (size_t)b * 3584 + g;
#pragma unroll
  for (int kp = 0; kp < 7; ++kp) {
    f16x8 hv;
    unsigned long long lb = 0;
#pragma unroll
    for (int e = 0; e < 8; ++e) {
      float f = prim_eval(kp, xv[e]);
      _Float16 fh = (_Float16)f;
      hv[e] = fh;
      lb |= (unsigned long long)enc_e5m2(f - (float)fh) << (8 * e);
    }
    *(f16x8*)&oh[kp * 512] = hv;
    *(unsigned long long*)&ol[kp * 512] = lb;
  }
}

// ---------------------------------------------------------------------------
// Featurize (layer-2 input): h [rows][512] fp32 -> out [rows][3584] fp16.
// ---------------------------------------------------------------------------
__global__ __launch_bounds__(256)
void featurize8(const float* __restrict__ in, _Float16* __restrict__ out) {
  int t = blockIdx.x * 256 + threadIdx.x;
  int b = t >> 6, g = (t & 63) * 8;
  const float* xp = in + (size_t)b * 512 + g;
  float4 a = *(const float4*)xp;
  float4 c = *(const float4*)(xp + 4);
  float xv[8] = {a.x, a.y, a.z, a.w, c.x, c.y, c.z, c.w};
  _Float16* o = out + (size_t)b * 3584 + g;
#pragma unroll
  for (int kp = 0; kp < 7; ++kp) {
    f16x8 v;
#pragma unroll
    for (int e = 0; e < 8; ++e) v[e] = cvh(prim_eval(kp, xv[e]));
    *(f16x8*)&o[kp * 512] = v;
  }
}

__global__ __launch_bounds__(256)
void cvt_half_k(const float* __restrict__ in, _Float16* __restrict__ out, int n) {
  int idx = blockIdx.x * 256 + threadIdx.x;
  if (idx < n) out[idx] = (_Float16)(in[idx] * PSCALE);
}

// ---------------------------------------------------------------------------
// Layer-1 GEMM (r7-proven): 3-term split GEMM on pre-featurized A.
// A-hi fp16 (swizzled), A-lo e5m2 bytes (16B-pair XOR-swizzled), B-hi/lo
// fp16 (swizzled). 128x128, BK=64, 4 waves, 56 KB LDS (2 blk/CU), 2-phase.
// ---------------------------------------------------------------------------
__global__ __launch_bounds__(256)
void gemm_l1_pre(const _Float16* __restrict__ Fhi, const unsigned char* __restrict__ FloB,
                 const _Float16* __restrict__ Wh, const _Float16* __restrict__ Wl,
                 const float* __restrict__ bias, float* __restrict__ H) {
  __shared__ __align__(16) _Float16 AhS[128 * 64];       // 16 KB
  __shared__ __align__(16) unsigned char AlB[128 * 64];  //  8 KB
  __shared__ __align__(16) _Float16 BhS[128 * 64];       // 16 KB
  __shared__ __align__(16) _Float16 BlS[128 * 64];       // 16 KB
  const int K = 3584;
  int lin = blockIdx.x;                 // 512 blocks
  int wg = (lin & 7) * 64 + (lin >> 3); // XCD-contiguous remap
  int bn = wg & 3, bm = wg >> 2;        // bn fast: col-blocks share A panel in XCD-L2
  int row0 = bm * 128, col0 = bn * 128;
  int tid = threadIdx.x, lane = tid & 63, wave = tid >> 6;
  int wm = wave >> 1, wn = wave & 1;
  int l16 = lane & 15, lh = lane >> 4;
  int sr = lane >> 3, sc = ((lane & 7) * 8) ^ (sr << 3);  // pre-swz src col (halves)
  int br = lane >> 2, bp_ = lane & 3;
  int bcs = (bp_ ^ ((br >> 1) & 3)) * 16;                 // pre-swz src col (bytes)

  f32x4 acc[4][4];
#pragma unroll
  for (int m = 0; m < 4; ++m)
#pragma unroll
    for (int n = 0; n < 4; ++n) acc[m][n] = (f32x4){0.f, 0.f, 0.f, 0.f};

  for (int kk0 = 0; kk0 < K; kk0 += 64) {
    const _Float16* Agh = Fhi + (size_t)row0 * K + kk0;
    const unsigned char* Agl = FloB + (size_t)row0 * K + kk0;
    const _Float16* Bgh = Wh + (size_t)col0 * K + kk0;
    const _Float16* Bgl = Wl + (size_t)col0 * K + kk0;
#pragma unroll
    for (int it = 0; it < 4; ++it) {
      int chunk = it * 4 + wave;          // 0..15
      int r = chunk * 8 + sr;
      size_t go = (size_t)r * K + sc;
      gload_lds16(Agh + go, AhS + chunk * 512);
      gload_lds16(Bgh + go, BhS + chunk * 512);
      gload_lds16(Bgl + go, BlS + chunk * 512);
    }
#pragma unroll
    for (int it = 0; it < 2; ++it) {
      int chunk = it * 4 + wave;          // 0..7, 16 rows each
      int r = chunk * 16 + br;
      gload_lds16(Agl + (size_t)r * K + bcs, AlB + chunk * 1024);
    }
    __syncthreads();
#pragma unroll
    for (int kc = 0; kc < 2; ++kc) {
      f16x8 ah[4], al[4];
#pragma unroll
      for (int m = 0; m < 4; ++m) {
        int row = wm * 64 + m * 16 + l16;
        ah[m] = *(const f16x8*)&AhS[swz(row, kc * 32 + lh * 8)];
        // A-lo: 8 e5m2 bytes (pair-swizzled) -> 8 fp16 (byte<<8)
        int cbyte = (kc * 32 + lh * 8) ^ (((row >> 1) & 3) << 4);
        uint2 d = *(const uint2*)&AlB[row * 64 + cbyte];
        union { unsigned u[4]; f16x8 v; } ex;
        ex.u[0] = ((d.x << 8) & 0xFF00u) | ((d.x << 16) & 0xFF000000u);
        ex.u[1] = ((d.x >> 8) & 0xFF00u) | (d.x & 0xFF000000u);
        ex.u[2] = ((d.y << 8) & 0xFF00u) | ((d.y << 16) & 0xFF000000u);
        ex.u[3] = ((d.y >> 8) & 0xFF00u) | (d.y & 0xFF000000u);
        al[m] = ex.v;
      }
#pragma unroll
      for (int n = 0; n < 4; ++n) {
        int ob = swz(wn * 64 + n * 16 + l16, kc * 32 + lh * 8);
        f16x8 bh = *(const f16x8*)&BhS[ob];
        f16x8 bl = *(const f16x8*)&BlS[ob];
#pragma unroll
        for (int m = 0; m < 4; ++m) {
          acc[m][n] = __builtin_amdgcn_mfma_f32_16x16x32_f16(ah[m], bh, acc[m][n], 0, 0, 0);
          acc[m][n] = __builtin_amdgcn_mfma_f32_16x16x32_f16(al[m], bh, acc[m][n], 0, 0, 0);
          acc[m][n] = __builtin_amdgcn_mfma_f32_16x16x32_f16(ah[m], bl, acc[m][n], 0, 0, 0);
        }
      }
    }
    __syncthreads();
  }

#pragma unroll
  for (int m = 0; m < 4; ++m) {
    int row = row0 + wm * 64 + m * 16 + lh * 4;
#pragma unroll
    for (int n = 0; n < 4; ++n) {
      int col = col0 + wn * 64 + n * 16 + l16;
      float bv = bias[col];
#pragma unroll
      for (int r = 0; r < 4; ++r)
        H[(size_t)(row + r) * 512 + col] = acc[m][n][r] * WDESCALE + bv;
    }
  }
}

// ---------------------------------------------------------------------------
// Plain fp16 GEMM, T3-pipelined (r8-proven): 128x128, 512 thr (2x4 waves),
// dbuf 64 KB (2 blk/CU). C = A * BT^T * outscale + bias.
// ---------------------------------------------------------------------------
template <bool OUT_HALF>
__global__ __launch_bounds__(512, 4)
void gemm_tn_pipe(const _Float16* __restrict__ A, const _Float16* __restrict__ BT,
                  const float* __restrict__ bias, void* __restrict__ C,
                  int M, int N, int K, int nbn_log2, int nwg, float outscale) {
  __shared__ __align__(16) _Float16 Ash[2][128 * 64];
  __shared__ __align__(16) _Float16 Bsh[2][128 * 64];
  int NT = K >> 6;
  int lin = blockIdx.x;
  int q = nwg >> 3;
  int wg = (lin & 7) * q + (lin >> 3);
  int bn = wg & ((1 << nbn_log2) - 1);
  int bm = wg >> nbn_log2;
  int row0 = bm * 128, col0 = bn * 128;
  int tid = threadIdx.x, lane = tid & 63, wave = tid >> 6;
  int wm = wave >> 2, wn = wave & 3;    // 2x4
  int l16 = lane & 15, lh = lane >> 4;
  int sr = lane >> 3, sc = ((lane & 7) * 8) ^ (sr << 3);

  const _Float16* Ag = A + (size_t)row0 * K;
  const _Float16* Bg = BT + (size_t)col0 * K;

  f32x4 acc[4][2];
#pragma unroll
  for (int m = 0; m < 4; ++m)
#pragma unroll
    for (int n = 0; n < 2; ++n) acc[m][n] = (f32x4){0.f, 0.f, 0.f, 0.f};

  auto stage = [&](int t, int p) {      // 4 vmem loads per thread
    int kk = t * 64;
#pragma unroll
    for (int it = 0; it < 2; ++it) {
      int chunk = it * 8 + wave;
      int r = chunk * 8 + sr;
      size_t go = (size_t)r * K + kk + sc;
      gload_lds16(Ag + go, &Ash[p][chunk * 512]);
      gload_lds16(Bg + go, &Bsh[p][chunk * 512]);
    }
  };

  stage(0, 0);
  PIPE_TAIL();

#pragma unroll 1
  for (int t = 0; t < NT; ++t) {
    int p = t & 1;
    if (t + 1 < NT) stage(t + 1, p ^ 1);
    __builtin_amdgcn_sched_barrier(0);
    __builtin_amdgcn_s_setprio(1);
#pragma unroll
    for (int kc = 0; kc < 2; ++kc) {
      f16x8 af[4], bf[2];
#pragma unroll
      for (int m = 0; m < 4; ++m)
        af[m] = *(const f16x8*)&Ash[p][swz(wm * 64 + m * 16 + l16, kc * 32 + lh * 8)];
#pragma unroll
      for (int n = 0; n < 2; ++n)
        bf[n] = *(const f16x8*)&Bsh[p][swz(wn * 32 + n * 16 + l16, kc * 32 + lh * 8)];
#pragma unroll
      for (int n = 0; n < 2; ++n)
#pragma unroll
        for (int m = 0; m < 4; ++m)
          acc[m][n] = __builtin_amdgcn_mfma_f32_16x16x32_f16(af[m], bf[n], acc[m][n], 0, 0, 0);
    }
    __builtin_amdgcn_s_setprio(0);
    PIPE_TAIL();
  }

#pragma unroll
  for (int m = 0; m < 4; ++m) {
    int row = row0 + wm * 64 + m * 16 + lh * 4;
#pragma unroll
    for (int n = 0; n < 2; ++n) {
      int col = col0 + wn * 32 + n * 16 + l16;
      float bv = bias[col];
#pragma unroll
      for (int r = 0; r < 4; ++r) {
        float v = acc[m][n][r] * outscale + bv;
        if (OUT_HALF)
          ((_Float16*)C)[(size_t)(row + r) * N + col] = cvh(v);
        else
          ((float*)C)[(size_t)(row + r) * N + col] = v;
      }
    }
  }
}

// ---------------------------------------------------------------------------
// Layer-1 fused GEMM (pipeline B fallback, proven): featurize in-loop.
// ---------------------------------------------------------------------------
__global__ __launch_bounds__(256, 2)
void gemm_l1_fused(const float* __restrict__ X, const _Float16* __restrict__ Wh,
                   const _Float16* __restrict__ Wl, const float* __restrict__ bias,
                   float* __restrict__ H) {
  __shared__ __align__(16) _Float16 AhS[128 * 64];
  __shared__ __align__(16) _Float16 AlS[128 * 64];
  __shared__ __align__(16) _Float16 BhS[128 * 64];
  __shared__ __align__(16) _Float16 BlS[128 * 64];
  const int K = 3584;
  int lin = blockIdx.x;
  int wg = (lin & 7) * 64 + (lin >> 3);
  int bn = wg & 3, bm = wg >> 2;
  int row0 = bm * 128, col0 = bn * 128;
  int tid = threadIdx.x, lane = tid & 63, wave = tid >> 6;
  int wm = wave >> 1, wn = wave & 1;
  int l16 = lane & 15, lh = lane >> 4;
  int sr = lane >> 3, sc = ((lane & 7) * 8) ^ (sr << 3);
  int ar = tid >> 3, ac = (tid & 7) * 8;

  f32x4 acc[4][4];
#pragma unroll
  for (int m = 0; m < 4; ++m)
#pragma unroll
    for (int n = 0; n < 4; ++n) acc[m][n] = (f32x4){0.f, 0.f, 0.f, 0.f};

#pragma unroll 1
  for (int kk0 = 0; kk0 < K; kk0 += 64) {
    int kp = kk0 >> 9, i0 = kk0 & 511;
    const _Float16* Bgh = Wh + (size_t)col0 * K + kk0;
    const _Float16* Bgl = Wl + (size_t)col0 * K + kk0;
#pragma unroll
    for (int it = 0; it < 4; ++it) {
      int chunk = it * 4 + wave;
      int r = chunk * 8 + sr;
      gload_lds16(Bgh + (size_t)r * K + sc, BhS + chunk * 512);
      gload_lds16(Bgl + (size_t)r * K + sc, BlS + chunk * 512);
    }
#pragma unroll
    for (int it = 0; it < 4; ++it) {
      int r = it * 32 + ar;
      const float* xp = X + (size_t)(row0 + r) * 512 + i0 + ac;
      float4 x01 = *(const float4*)xp;
      float4 x23 = *(const float4*)(xp + 4);
      float xv[8] = {x01.x, x01.y, x01.z, x01.w, x23.x, x23.y, x23.z, x23.w};
      f16x8 hv, lv;
#pragma unroll
      for (int e = 0; e < 8; ++e) {
        float f = prim_eval(kp, xv[e]);
        _Float16 fh = (_Float16)f;
        hv[e] = fh;
        lv[e] = (_Float16)(f - (float)fh);
      }
      int wo = swz(r, ac);
      *(f16x8*)&AhS[wo] = hv;
      *(f16x8*)&AlS[wo] = lv;
    }
    __syncthreads();
#pragma unroll
    for (int kc = 0; kc < 2; ++kc) {
      f16x8 ah[4], al[4];
#pragma unroll
      for (int m = 0; m < 4; ++m) {
        int off = swz(wm * 64 + m * 16 + l16, kc * 32 + lh * 8);
        ah[m] = *(const f16x8*)&AhS[off];
        al[m] = *(const f16x8*)&AlS[off];
      }
#pragma unroll
      for (int n = 0; n < 4; ++n) {
        int ob = swz(wn * 64 + n * 16 + l16, kc * 32 + lh * 8);
        f16x8 bh = *(const f16x8*)&BhS[ob];
        f16x8 bl = *(const f16x8*)&BlS[ob];
#pragma unroll
        for (int m = 0; m < 4; ++m) {
          acc[m][n] = __builtin_amdgcn_mfma_f32_16x16x32_f16(ah[m], bh, acc[m][n], 0, 0, 0);
          acc[m][n] = __builtin_amdgcn_mfma_f32_16x16x32_f16(al[m], bh, acc[m][n], 0, 0, 0);
          acc[m][n] = __builtin_amdgcn_mfma_f32_16x16x32_f16(ah[m], bl, acc[m][n], 0, 0, 0);
        }
      }
    }
    __syncthreads();
  }

#pragma unroll
  for (int m = 0; m < 4; ++m) {
    int row = row0 + wm * 64 + m * 16 + lh * 4;
#pragma unroll
    for (int n = 0; n < 4; ++n) {
      int col = col0 + wn * 64 + n * 16 + l16;
      float bv = bias[col];
#pragma unroll
      for (int r = 0; r < 4; ++r)
        H[(size_t)(row + r) * 512 + col] = acc[m][n][r] * WDESCALE + bv;
    }
  }
}

// ---------------------------------------------------------------------------
// Plain fp16 GEMM (16x16 2-phase, proven): fallback path B.
// ---------------------------------------------------------------------------
template <bool OUT_HALF>
__global__ __launch_bounds__(256)
void gemm_tn(const _Float16* __restrict__ A, const _Float16* __restrict__ BT,
             const float* __restrict__ bias, void* __restrict__ C,
             int M, int N, int K, int nbn_log2, int nwg, float outscale) {
  __shared__ __align__(16) _Float16 Ash[128 * 64];
  __shared__ __align__(16) _Float16 Bsh[128 * 64];
  int lin = blockIdx.x;
  int q = nwg >> 3;
  int wg = (lin & 7) * q + (lin >> 3);
  int bn = wg & ((1 << nbn_log2) - 1);
  int bm = wg >> nbn_log2;
  int row0 = bm * 128, col0 = bn * 128;
  int tid = threadIdx.x, lane = tid & 63, wave = tid >> 6;
  int wm = wave >> 1, wn = wave & 1;
  int l16 = lane & 15, lh = lane >> 4;
  int sr = lane >> 3;
  int sc = ((lane & 7) * 8) ^ (sr << 3);

  f32x4 acc[4][4];
#pragma unroll
  for (int m = 0; m < 4; ++m)
#pragma unroll
    for (int n = 0; n < 4; ++n) acc[m][n] = (f32x4){0.f, 0.f, 0.f, 0.f};

  for (int kk0 = 0; kk0 < K; kk0 += 64) {
    const _Float16* Ag = A + (size_t)row0 * K + kk0;
    const _Float16* Bg = BT + (size_t)col0 * K + kk0;
#pragma unroll
    for (int it = 0; it < 4; ++it) {
      int chunk = it * 4 + wave;
      int r = chunk * 8 + sr;
      gload_lds16(Ag + (size_t)r * K + sc, Ash + chunk * 512);
      gload_lds16(Bg + (size_t)r * K + sc, Bsh + chunk * 512);
    }
    __syncthreads();
#pragma unroll
    for (int kc = 0; kc < 2; ++kc) {
      f16x8 af[4], bf[4];
#pragma unroll
      for (int m = 0; m < 4; ++m)
        af[m] = *(const f16x8*)&Ash[swz(wm * 64 + m * 16 + l16, kc * 32 + lh * 8)];
#pragma unroll
      for (int n = 0; n < 4; ++n)
        bf[n] = *(const f16x8*)&Bsh[swz(wn * 64 + n * 16 + l16, kc * 32 + lh * 8)];
#pragma unroll
      for (int m = 0; m < 4; ++m)
#pragma unroll
        for (int n = 0; n < 4; ++n)
          acc[m][n] = __builtin_amdgcn_mfma_f32_16x16x32_f16(af[m], bf[n], acc[m][n], 0, 0, 0);
    }
    __syncthreads();
  }

#pragma unroll
  for (int m = 0; m < 4; ++m) {
    int row = row0 + wm * 64 + m * 16 + lh * 4;
#pragma unroll
    for (int n = 0; n < 4; ++n) {
      int col = col0 + wn * 64 + n * 16 + l16;
      float bv = bias[col];
#pragma unroll
      for (int r = 0; r < 4; ++r) {
        float v = acc[m][n][r] * outscale + bv;
        if (OUT_HALF)
          ((_Float16*)C)[(size_t)(row + r) * N + col] = cvh(v);
        else
          ((float*)C)[(size_t)(row + r) * N + col] = v;
      }
    }
  }
}

// ---------------------------------------------------------------------------
extern "C" void kernel_launch(void* const* d_in, const int* in_sizes, int n_in,
                              void* d_out, int out_size, void* d_ws, size_t ws_size,
                              hipStream_t stream) {
  const float* x  = (const float*)d_in[0];
  const float* a0 = (const float*)d_in[1];
  const float* s0 = (const float*)d_in[2];
  const float* b0 = (const float*)d_in[3];
  const float* a1 = (const float*)d_in[4];
  const float* s1 = (const float*)d_in[5];
  const float* b1 = (const float*)d_in[6];
  const float* W  = (const float*)d_in[7];
  const float* bb = (const float*)d_in[8];

  const int Bn = 16384, D = 512, KK = 3584, DOUT = 256;
  const size_t szF  = (size_t)Bn * KK * 2;  // 117,440,512
  const size_t szFb = (size_t)Bn * KK;      //  58,720,256 (byte lo)
  const size_t szH  = (size_t)Bn * D * 4;   //  33,554,432
  const size_t szW  = (size_t)D * KK * 2;   //   3,670,016
  const size_t szP  = (size_t)DOUT * D * 2; //     262,144
  const size_t needA = szF + szFb + szH + 3 * szW + szP + 4096;  // ~221.0 MB

  if (ws_size >= needA) {
    // ---- pipeline A: pre-featurized hi/byte-lo (r7) + piped l2/proj (r8) ----
    char* p = (char*)d_ws;
    _Float16*      Fhi  = (_Float16*)p; p += szF;       // reused as layer-2 Afeat
    unsigned char* FloB = (unsigned char*)p; p += szFb;
    float*    h     = (float*)p;
    _Float16* ghalf = (_Float16*)p; p += szH;
    _Float16* Wh0   = (_Float16*)p; p += szW;
    _Float16* Wl0   = (_Float16*)p; p += szW;
    _Float16* Wh1   = (_Float16*)p; p += szW;
    _Float16* WpT   = (_Float16*)p; p += szP;
    float*    biasv = (float*)p;

    prep_weights<true ><<<dim3(512), dim3(512), 0, stream>>>(a0, s0, b0, Wh0, Wl0, biasv);
    prep_weights<false><<<dim3(512), dim3(512), 0, stream>>>(a1, s1, b1, Wh1, nullptr, biasv + 512);
    cvt_half_k<<<dim3(512), dim3(256), 0, stream>>>(W, WpT, DOUT * D);

    featurize_hilo<<<dim3(Bn * 64 / 256), dim3(256), 0, stream>>>(x, Fhi, FloB);
    gemm_l1_pre<<<dim3(512), dim3(256), 0, stream>>>(Fhi, FloB, Wh0, Wl0, biasv, h);

    featurize8<<<dim3(Bn * 64 / 256), dim3(256), 0, stream>>>(h, Fhi);
    gemm_tn_pipe<true><<<dim3(512), dim3(512), 0, stream>>>(Fhi, Wh1, biasv + 512, ghalf,
                                                            Bn, D, KK, 2, 512, WDESCALE);

    gemm_tn_pipe<false><<<dim3(256), dim3(512), 0, stream>>>(ghalf, WpT, bb, (float*)d_out,
                                                             Bn, DOUT, D, 1, 256, PDESCALE);
  } else {
    // ---- pipeline B (proven fallback): fused featurize layer-1 ----
    char* p = (char*)d_ws;
    _Float16* Afeat = (_Float16*)p;
    _Float16* Wh0   = (_Float16*)p;
    _Float16* Wl0   = (_Float16*)(p + szW);
    p += szF;
    float*    h     = (float*)p;
    _Float16* ghalf = (_Float16*)p;
    p += szH;
    _Float16* Wh1   = (_Float16*)p; p += szW;
    _Float16* WpT   = (_Float16*)p; p += szP;
    float*    biasv = (float*)p;

    prep_weights<true ><<<dim3(512), dim3(512), 0, stream>>>(a0, s0, b0, Wh0, Wl0, biasv);
    prep_weights<false><<<dim3(512), dim3(512), 0, stream>>>(a1, s1, b1, Wh1, nullptr, biasv + 512);
    cvt_half_k<<<dim3(512), dim3(256), 0, stream>>>(W, WpT, DOUT * D);

    gemm_l1_fused<<<dim3(512), dim3(256), 0, stream>>>(x, Wh0, Wl0, biasv, h);

    featurize8<<<dim3(Bn * 64 / 256), dim3(256), 0, stream>>>(h, Afeat);
    gemm_tn<true><<<dim3(512), dim3(256), 0, stream>>>(Afeat, Wh1, biasv + 512, ghalf,
                                                       Bn, D, KK, 2, 512, WDESCALE);

    gemm_tn<false><<<dim3(256), dim3(256), 0, stream>>>(ghalf, WpT, bb, (float*)d_out,
                                                        Bn, DOUT, D, 1, 256, PDESCALE);
  }
}